// Round 6
// baseline (102.791 us; speedup 1.0000x reference)
//
#include <hip/hip_runtime.h>

#define CDIM 256
#define SCALING 0.17677669529663687f  // 32^-0.5

typedef _Float16 f16;
typedef f16 f16x4 __attribute__((ext_vector_type(4)));
typedef f16 f16x8 __attribute__((ext_vector_type(8)));
typedef float f32x4 __attribute__((ext_vector_type(4)));

// Standard gfx950 16x16x32 f16 fragment mapping (m89-verified D; bench-verified A/B):
//   A[m][k]: lane l, reg j  ->  m = l&15,          k = 8*(l>>4) + j   (k contiguous)
//   B[k][n]: lane l, reg j  ->  k = 8*(l>>4) + j,  n = l&15           (k contiguous)
//   D[m][n]: lane l, reg r  ->  m = 4*(l>>4) + r,  n = l&15
#define MFMA(a, b, c) __builtin_amdgcn_mfma_f32_16x16x32_f16(a, b, c, 0, 0, 0)

// ---------------- K0: W2_hd = scaling * wk_hd^T @ wq_hd ; b2 ; wv -> f16 ----------------
// grid (32 ci-octs, 8 hd) x 256 (t = cx)
__global__ __launch_bounds__(256) void k_prep_w2(const float* __restrict__ wq,
                                                 const float* __restrict__ bq,
                                                 const float* __restrict__ wk,
                                                 const float* __restrict__ wv,
                                                 f16* __restrict__ W2h,
                                                 float* __restrict__ b2,
                                                 f16* __restrict__ wvh) {
  __shared__ float wk_s[32][8];
  const int t = threadIdx.x, ciO = blockIdx.x, hd = blockIdx.y;
  {
    int j = t >> 3, c8 = t & 7;
    wk_s[j][c8] = wk[(hd * 32 + j) * CDIM + ciO * 8 + c8];
    // convert a 32x8 slice of wv while we're here
    int idx = (hd * 32 + j) * CDIM + ciO * 8 + c8;
    wvh[idx] = (f16)wv[idx];
  }
  float wq_r[32];
#pragma unroll
  for (int j = 0; j < 32; ++j) wq_r[j] = wq[(hd * 32 + j) * CDIM + t];
  __syncthreads();
  for (int c8 = 0; c8 < 8; ++c8) {
    float acc = 0.f;
#pragma unroll
    for (int j = 0; j < 32; ++j) acc = fmaf(wq_r[j], wk_s[j][c8], acc);
    W2h[(size_t)(hd * CDIM + ciO * 8 + c8) * CDIM + t] = (f16)(acc * SCALING);
  }
  if (t < 8) {
    float a = 0.f;
    for (int j = 0; j < 32; ++j) a = fmaf(wk_s[j][t], bq[hd * 32 + j], a);
    b2[hd * CDIM + ciO * 8 + t] = a * SCALING;
  }
}

// ---------------- K1: qk[b][pix][hd][ci] = W2_hd @ x + b2 ; gate ----------------
// grid (16 pix-64-slices, 8 hd, nb) x 256. M=256ci, N=64pix, K=256cx.
__global__ __launch_bounds__(256, 2) void k_qkw2(const float* __restrict__ x,
                                                 const f16* __restrict__ W2h,
                                                 const float* __restrict__ b2,
                                                 const float* __restrict__ wg,
                                                 const float* __restrict__ bg,
                                                 f16* __restrict__ qk,
                                                 float* __restrict__ gw, int b0) {
  __shared__ __align__(16) f16 A_l[256 * 40];  // [ci][32cx + 8 pad]  20480 B
  __shared__ __align__(16) f16 B_l[64 * 40];   // [pix][32cx + 8 pad]  5120 B
  const int t = threadIdx.x;
  const int p16 = blockIdx.x, hd = blockIdx.y, bz = blockIdx.z;
  const int bb = b0 + bz;
  const int lane = t & 63, wid = t >> 6, l15 = lane & 15, h4 = lane >> 4;
  f32x4 acc[4][4] = {};
  float gacc = 0.f;

  for (int kb = 0; kb < 8; ++kb) {
    __syncthreads();
    // stage A: W2_hd[:, kb*32 .. +32] (16 KB)
#pragma unroll
    for (int it = 0; it < 4; ++it) {
      int e = it * 256 + t, ci = e >> 2, q = e & 3;
      *(f16x8*)(A_l + ci * 40 + q * 8) =
          *(const f16x8*)(W2h + (size_t)(hd * CDIM + ci) * CDIM + kb * 32 + q * 8);
    }
    // stage B transposed: x[kb*32+cx][p16*64 + p] -> B_l[p][cx]
#pragma unroll
    for (int it = 0; it < 2; ++it) {
      int e = it * 256 + t, cx = e >> 4, p4 = e & 15;
      float4 v = *(const float4*)(x + (size_t)(bb * CDIM + kb * 32 + cx) * 1024 +
                                  p16 * 64 + p4 * 4);
      B_l[(p4 * 4 + 0) * 40 + cx] = (f16)v.x;
      B_l[(p4 * 4 + 1) * 40 + cx] = (f16)v.y;
      B_l[(p4 * 4 + 2) * 40 + cx] = (f16)v.z;
      B_l[(p4 * 4 + 3) * 40 + cx] = (f16)v.w;
    }
    __syncthreads();
    // gate partial (hd==0, wave 3): pixel = lane
    if (hd == 0 && wid == 3) {
#pragma unroll
      for (int cx = 0; cx < 32; ++cx)
        gacc = fmaf(wg[kb * 32 + cx], (float)B_l[lane * 40 + cx], gacc);
    }
    f16x8 a[4], bf[4];
#pragma unroll
    for (int mt = 0; mt < 4; ++mt)
      a[mt] = *(const f16x8*)(A_l + (wid * 64 + mt * 16 + l15) * 40 + h4 * 8);
#pragma unroll
    for (int nt = 0; nt < 4; ++nt)
      bf[nt] = *(const f16x8*)(B_l + (nt * 16 + l15) * 40 + h4 * 8);
#pragma unroll
    for (int mt = 0; mt < 4; ++mt)
#pragma unroll
      for (int nt = 0; nt < 4; ++nt) acc[mt][nt] = MFMA(a[mt], bf[nt], acc[mt][nt]);
  }
  // epilogue: + b2, f16, store qk[b][pix][hd][ci]
#pragma unroll
  for (int mt = 0; mt < 4; ++mt) {
    int ci0 = wid * 64 + mt * 16 + h4 * 4;
    float4 bvv = *(const float4*)(b2 + hd * CDIM + ci0);
#pragma unroll
    for (int nt = 0; nt < 4; ++nt) {
      int pix = p16 * 64 + nt * 16 + l15;
      union { f16 h[4]; unsigned long long u; } P;
      P.h[0] = (f16)(acc[mt][nt][0] + bvv.x);
      P.h[1] = (f16)(acc[mt][nt][1] + bvv.y);
      P.h[2] = (f16)(acc[mt][nt][2] + bvv.z);
      P.h[3] = (f16)(acc[mt][nt][3] + bvv.w);
      *(unsigned long long*)(qk + ((size_t)(bz * 1024 + pix) * 8 + hd) * CDIM + ci0) = P.u;
    }
  }
  if (hd == 0 && wid == 3)
    gw[bz * 1024 + p16 * 64 + lane] = 1.f / (1.f + __expf(-(gacc + bg[0])));
}

// ---------------- K2: fully fused local attention + output projection ----------------
// block (h, w4, b): 4 query pixels, wave w owns pixel w in P3/P5'. 3 barriers, no asm.
// P3 : logits[16hd][16p] = qk[16hd][256ci] @ feat_pci[256ci][16p]      (8 MFMA, A global)
// P5': faT[hd][ci]       = attn[16hd][32p] @ feat_cip[32p][16ci]       (16 MFMA)
//      fa lives in LDS, aliased onto the dead pci buffer.
// P6 : out[c][pix]       = (wv[c][256ci] @ fa[256ci][pix..] + bv)*gw   (32 MFMA/wave, A global)
__global__ __launch_bounds__(256, 2) void k_attn(const float* __restrict__ feat,
                                                 const f16* __restrict__ qk,
                                                 const f16* __restrict__ wvh,
                                                 const float* __restrict__ bv,
                                                 const float* __restrict__ gw,
                                                 float* __restrict__ out, int b0) {
  __shared__ __align__(16) f16 featb_cip[4 * 4128];  // 33024 B [w][256ci][16p] +32 zero pad/w
  __shared__ __align__(16) f16 smem2[4 * 4224];      // 33792 B pci: [w][16p][256ci+8]
                                                     //          then fa: [8hd][4pix][264ci]
  __shared__ __align__(16) f16 attn_l[4 * 16 * 32];  //  4096 B [w][16hd][32p]
  const int t = threadIdx.x;
  const int h = blockIdx.x, w4 = blockIdx.y, bz = blockIdx.z;
  const int bb = b0 + bz;
  const int lane = t & 63, w = t >> 6, l15 = lane & 15, h4 = lane >> 4;
  const int pixb = h * 32 + w4 * 4;

  {  // zero attn buffer (p>=16 stays 0 = K-padding; hd>=8 rows stay 0)
    f16x8 z = {};
    *(f16x8*)(attn_l + t * 8) = z;
  }
  if (t < 128) {  // zero cip pad (P5' B k=16..31 of each w's last ci row reads it)
    int wi = t >> 5, i = t & 31;
    featb_cip[wi * 4128 + 4096 + i] = (f16)0;
  }
  // stage feat patch (4 rows x 16 cols x 256 ch f32) into both f16 layouts
  const float* fb = feat + (size_t)bb * (CDIM * 16384) + (h * 4) * 128 + w4 * 16;
#pragma unroll
  for (int it = 0; it < 16; ++it) {
    int e = it * 256 + t, j4 = e & 3, r = (e >> 2) & 3, ci = e >> 4;
    float4 v = *(const float4*)(fb + (size_t)ci * 16384 + r * 128 + j4 * 4);
    f16x4 hv;
    hv[0] = (f16)v.x; hv[1] = (f16)v.y; hv[2] = (f16)v.z; hv[3] = (f16)v.w;
    *(f16x4*)(featb_cip + j4 * 4128 + ci * 16 + r * 4) = hv;  // p = r*4 + 0..3
    int pb = j4 * 4224 + ci;
    smem2[pb + (r * 4 + 0) * 264] = hv[0];
    smem2[pb + (r * 4 + 1) * 264] = hv[1];
    smem2[pb + (r * 4 + 2) * 264] = hv[2];
    smem2[pb + (r * 4 + 3) * 264] = hv[3];
  }
  __syncthreads();

  // ---- P3: logits via MFMA. A from global (L2-hot qk), rows 8-15 alias 0-7 ----
  const f16* qkg = qk + ((size_t)(bz * 1024 + pixb + w) * 8 + (l15 & 7)) * CDIM;
  const f16* fpci = smem2 + w * 4224 + l15 * 264;
  f32x4 acc = {};
#pragma unroll
  for (int kb = 0; kb < 8; ++kb) {
    f16x8 a = *(const f16x8*)(qkg + kb * 32 + h4 * 8);    // A[hd][ci]
    f16x8 bf = *(const f16x8*)(fpci + kb * 32 + h4 * 8);  // B[ci][p]
    acc = MFMA(a, bf, acc);
  }
  // ---- softmax over p (= lane&15), hd = 4*h4 + reg (h4<2 real, rest dupes) ----
  float at[4];
#pragma unroll
  for (int r = 0; r < 4; ++r) {
    float m = acc[r];
    m = fmaxf(m, __shfl_xor(m, 1, 64));
    m = fmaxf(m, __shfl_xor(m, 2, 64));
    m = fmaxf(m, __shfl_xor(m, 4, 64));
    m = fmaxf(m, __shfl_xor(m, 8, 64));
    float e = __expf(acc[r] - m);
    float s = e;
    s += __shfl_xor(s, 1, 64);
    s += __shfl_xor(s, 2, 64);
    s += __shfl_xor(s, 4, 64);
    s += __shfl_xor(s, 8, 64);
    at[r] = e / s;
  }
  if (h4 < 2) {
#pragma unroll
    for (int r = 0; r < 4; ++r) attn_l[(w * 16 + h4 * 4 + r) * 32 + l15] = (f16)at[r];
  }
  __syncthreads();  // all P3 pci reads done; attn_l complete -> smem2 reusable as fa

  // ---- P5': faT[hd][nt*16+l15] = attn[hd][32p] @ feat_cip[32p][16ci] ----
  {
    f16x8 afr = *(const f16x8*)(attn_l + (w * 16 + l15) * 32 + h4 * 8);  // A[m=hd][k=p]
    const f16* fw = featb_cip + w * 4128;
    f32x4 zero = {};
#pragma unroll
    for (int nt = 0; nt < 16; ++nt) {
      f16x8 b5 = *(const f16x8*)(fw + (nt * 16 + l15) * 16 + h4 * 8);  // B[k=p][n=ci]
      f32x4 d = MFMA(afr, b5, zero);
      if (h4 < 2) {  // m = 4*h4 + r = hd (0..7 real)
#pragma unroll
        for (int r = 0; r < 4; ++r)
          smem2[((h4 * 4 + r) * 4 + w) * 264 + nt * 16 + l15] = (f16)d[r];
      }
    }
  }
  __syncthreads();

  // ---- P6: out = wv @ fa + bv, * gw. Wave w handles heads {2w, 2w+1}. ----
  {
    const float gwv = gw[bz * 1024 + pixb + (l15 & 3)];
#pragma unroll
    for (int hd2 = 0; hd2 < 2; ++hd2) {
      const int hd = w * 2 + hd2;
#pragma unroll
      for (int mt = 0; mt < 2; ++mt) {
        f32x4 acc6 = {};
#pragma unroll
        for (int kb = 0; kb < 8; ++kb) {
          // A[m=c][k=ci] from global wvh (L2/L3-hot)
          f16x8 a6 = *(const f16x8*)(wvh + (size_t)(hd * 32 + mt * 16 + l15) * CDIM +
                                     kb * 32 + h4 * 8);
          // B[k=ci][n=pix] from fa LDS; lanes l15>=4 clamp (their D cols discarded)
          f16x8 b6 = *(const f16x8*)(smem2 + (hd * 4 + (l15 & 3)) * 264 + kb * 32 + h4 * 8);
          acc6 = MFMA(a6, b6, acc6);
        }
        if (l15 < 4) {  // n = l15 = pix; m = 4*h4 + r -> c
          float4 bv4 = *(const float4*)(bv + hd * 32 + mt * 16 + h4 * 4);
          const int c0 = hd * 32 + mt * 16 + h4 * 4;
#pragma unroll
          for (int r = 0; r < 4; ++r) {
            float o = (acc6[r] + ((const float*)&bv4)[r]) * gwv;
            out[(size_t)(bb * CDIM + c0 + r) * 1024 + pixb + l15] = o;
          }
        }
      }
    }
  }
}

// ---------------- launcher ----------------
extern "C" void kernel_launch(void* const* d_in, const int* in_sizes, int n_in,
                              void* d_out, int out_size, void* d_ws, size_t ws_size,
                              hipStream_t stream) {
  const float* x = (const float*)d_in[0];
  const float* feat = (const float*)d_in[1];
  const float* wq = (const float*)d_in[2];
  const float* bq = (const float*)d_in[3];
  const float* wk = (const float*)d_in[4];
  // d_in[5] = bk: constant over grid positions -> cancels in softmax, unused
  const float* wv = (const float*)d_in[6];
  const float* bv = (const float*)d_in[7];
  const float* wg = (const float*)d_in[8];
  const float* bg = (const float*)d_in[9];
  float* out = (float*)d_out;

  char* ws = (char*)d_ws;
  f16* W2h = (f16*)ws;                 // 1,048,576 B
  float* b2 = (float*)(ws + 1048576);  //     8,192 B
  f16* wvh = (f16*)(ws + 1056768);     //   131,072 B
  char* dyn = ws + 1187840;

  k_prep_w2<<<dim3(32, 8), 256, 0, stream>>>(wq, bq, wk, wv, W2h, b2, wvh);

  const size_t QK = 4194304, GW = 4096;  // per batch
  if (ws_size >= 1187840 + 8 * (QK + GW)) {
    f16* qk = (f16*)dyn;
    float* gwp = (float*)(dyn + 8 * QK);
    k_qkw2<<<dim3(16, 8, 8), 256, 0, stream>>>(x, W2h, b2, wg, bg, qk, gwp, 0);
    k_attn<<<dim3(32, 8, 8), 256, 0, stream>>>(feat, qk, wvh, bv, gwp, out, 0);
  } else {  // per-batch fallback (~5.4 MB workspace)
    f16* qk = (f16*)dyn;
    float* gwp = (float*)(dyn + QK);
    for (int b = 0; b < 8; ++b) {
      k_qkw2<<<dim3(16, 8, 1), 256, 0, stream>>>(x, W2h, b2, wg, bg, qk, gwp, b);
      k_attn<<<dim3(32, 8, 1), 256, 0, stream>>>(feat, qk, wvh, bv, gwp, out, b);
    }
  }
}

// Round 8
// 80.355 us; speedup vs baseline: 1.2792x; 1.2792x over previous
//
#include <hip/hip_runtime.h>

#define CDIM 256
#define SCALING 0.17677669529663687f  // 32^-0.5

typedef _Float16 f16;
typedef f16 f16x4 __attribute__((ext_vector_type(4)));
typedef f16 f16x8 __attribute__((ext_vector_type(8)));
typedef float f32x4 __attribute__((ext_vector_type(4)));

// Standard gfx950 16x16x32 f16 fragment mapping (m89-verified D; bench-verified A/B):
//   A[m][k]: lane l, reg j  ->  m = l&15,          k = 8*(l>>4) + j   (k contiguous)
//   B[k][n]: lane l, reg j  ->  k = 8*(l>>4) + j,  n = l&15           (k contiguous)
//   D[m][n]: lane l, reg r  ->  m = 4*(l>>4) + r,  n = l&15
#define MFMA(a, b, c) __builtin_amdgcn_mfma_f32_16x16x32_f16(a, b, c, 0, 0, 0)

__device__ __forceinline__ unsigned pack2(float a, float b) {
  union { f16 h[2]; unsigned u; } r;
  r.h[0] = (f16)a;
  r.h[1] = (f16)b;
  return r.u;
}

// ---------------- K0: W2_hd = scaling * wk_hd^T @ wq_hd ; b2 ; wv -> f16 ----------------
// grid (32 ci-octs, 8 hd) x 256 (t = cx)
__global__ __launch_bounds__(256) void k_prep_w2(const float* __restrict__ wq,
                                                 const float* __restrict__ bq,
                                                 const float* __restrict__ wk,
                                                 const float* __restrict__ wv,
                                                 f16* __restrict__ W2h,
                                                 float* __restrict__ b2,
                                                 f16* __restrict__ wvh) {
  __shared__ float wk_s[32][8];
  const int t = threadIdx.x, ciO = blockIdx.x, hd = blockIdx.y;
  {
    int j = t >> 3, c8 = t & 7;
    wk_s[j][c8] = wk[(hd * 32 + j) * CDIM + ciO * 8 + c8];
    int idx = (hd * 32 + j) * CDIM + ciO * 8 + c8;
    wvh[idx] = (f16)wv[idx];
  }
  float wq_r[32];
#pragma unroll
  for (int j = 0; j < 32; ++j) wq_r[j] = wq[(hd * 32 + j) * CDIM + t];
  __syncthreads();
  for (int c8 = 0; c8 < 8; ++c8) {
    float acc = 0.f;
#pragma unroll
    for (int j = 0; j < 32; ++j) acc = fmaf(wq_r[j], wk_s[j][c8], acc);
    W2h[(size_t)(hd * CDIM + ciO * 8 + c8) * CDIM + t] = (f16)(acc * SCALING);
  }
  if (t < 8) {
    float a = 0.f;
    for (int j = 0; j < 32; ++j) a = fmaf(wk_s[j][t], bq[hd * 32 + j], a);
    b2[hd * CDIM + ciO * 8 + t] = a * SCALING;
  }
}

// ---------------- K1: qk[b][pix][hd][ci] = W2_hd @ x + b2 ; gate ----------------
// grid (16 pix-64-slices, 8 hd, nb) x 256. M=256ci, N=64pix, K=256cx.
__global__ __launch_bounds__(256, 2) void k_qkw2(const float* __restrict__ x,
                                                 const f16* __restrict__ W2h,
                                                 const float* __restrict__ b2,
                                                 const float* __restrict__ wg,
                                                 const float* __restrict__ bg,
                                                 f16* __restrict__ qk,
                                                 float* __restrict__ gw, int b0) {
  __shared__ __align__(16) f16 A_l[256 * 40];  // [ci][32cx + 8 pad]  20480 B
  __shared__ __align__(16) f16 B_l[64 * 40];   // [pix][32cx + 8 pad]  5120 B
  const int t = threadIdx.x;
  const int p16 = blockIdx.x, hd = blockIdx.y, bz = blockIdx.z;
  const int bb = b0 + bz;
  const int lane = t & 63, wid = t >> 6, l15 = lane & 15, h4 = lane >> 4;
  f32x4 acc[4][4] = {};
  float gacc = 0.f;

  for (int kb = 0; kb < 8; ++kb) {
    __syncthreads();
#pragma unroll
    for (int it = 0; it < 4; ++it) {
      int e = it * 256 + t, ci = e >> 2, q = e & 3;
      *(f16x8*)(A_l + ci * 40 + q * 8) =
          *(const f16x8*)(W2h + (size_t)(hd * CDIM + ci) * CDIM + kb * 32 + q * 8);
    }
#pragma unroll
    for (int it = 0; it < 2; ++it) {
      int e = it * 256 + t, cx = e >> 4, p4 = e & 15;
      float4 v = *(const float4*)(x + (size_t)(bb * CDIM + kb * 32 + cx) * 1024 +
                                  p16 * 64 + p4 * 4);
      B_l[(p4 * 4 + 0) * 40 + cx] = (f16)v.x;
      B_l[(p4 * 4 + 1) * 40 + cx] = (f16)v.y;
      B_l[(p4 * 4 + 2) * 40 + cx] = (f16)v.z;
      B_l[(p4 * 4 + 3) * 40 + cx] = (f16)v.w;
    }
    __syncthreads();
    if (hd == 0 && wid == 3) {
#pragma unroll
      for (int cx = 0; cx < 32; ++cx)
        gacc = fmaf(wg[kb * 32 + cx], (float)B_l[lane * 40 + cx], gacc);
    }
    f16x8 a[4], bf[4];
#pragma unroll
    for (int mt = 0; mt < 4; ++mt)
      a[mt] = *(const f16x8*)(A_l + (wid * 64 + mt * 16 + l15) * 40 + h4 * 8);
#pragma unroll
    for (int nt = 0; nt < 4; ++nt)
      bf[nt] = *(const f16x8*)(B_l + (nt * 16 + l15) * 40 + h4 * 8);
#pragma unroll
    for (int mt = 0; mt < 4; ++mt)
#pragma unroll
      for (int nt = 0; nt < 4; ++nt) acc[mt][nt] = MFMA(a[mt], bf[nt], acc[mt][nt]);
  }
#pragma unroll
  for (int mt = 0; mt < 4; ++mt) {
    int ci0 = wid * 64 + mt * 16 + h4 * 4;
    float4 bvv = *(const float4*)(b2 + hd * CDIM + ci0);
#pragma unroll
    for (int nt = 0; nt < 4; ++nt) {
      int pix = p16 * 64 + nt * 16 + l15;
      union { f16 h[4]; unsigned long long u; } P;
      P.h[0] = (f16)(acc[mt][nt][0] + bvv.x);
      P.h[1] = (f16)(acc[mt][nt][1] + bvv.y);
      P.h[2] = (f16)(acc[mt][nt][2] + bvv.z);
      P.h[3] = (f16)(acc[mt][nt][3] + bvv.w);
      *(unsigned long long*)(qk + ((size_t)(bz * 1024 + pix) * 8 + hd) * CDIM + ci0) = P.u;
    }
  }
  if (hd == 0 && wid == 3)
    gw[bz * 1024 + p16 * 64 + lane] = 1.f / (1.f + __expf(-(gacc + bg[0])));
}

// ---------------- K2: fused local attention (single layout, 1 barrier, 4 blk/CU) ------
// block (h, w4, b): 4 query pixels, wave w owns pixel w. LDS = 40960 B exactly.
// cip[px][256ci][18] (16 p + 2 ZEROED pad; stride-18 -> conflict-free P3/P5 reads)
// P3 : logits[16hd][16p] = qk[16hd][256ci] @ feat[256ci][16p]  (8 MFMA; B via 8 u16 reads)
// P5'': fa[16ci][16hd]   = feat[256ci][32p-junk] @ attn[32p][16hd]  (16 MFMA; attn rows
//       16-31 ZERO kill the junk — junk must be FINITE, hence the pad zeroing)
__global__ __launch_bounds__(256, 4) void k_attn(const float* __restrict__ feat,
                                                 const f16* __restrict__ qk,
                                                 f16* __restrict__ fa, int b0) {
  __shared__ __align__(16) f16 cip[4 * 4608];    // 36864 B [px][ci][18]
  __shared__ __align__(16) f16 attn_l[4 * 512];  //  4096 B [w][32p][16hd]
  const int t = threadIdx.x;
  const int h = blockIdx.x, w4 = blockIdx.y, bz = blockIdx.z;
  const int bb = b0 + bz;
  const int lane = t & 63, w = t >> 6, l15 = lane & 15, h4 = lane >> 4;
  const int pixb = h * 32 + w4 * 4;

  {  // zero attn_l: p>=16 rows = K-padding zeros; hd>=8 cols = zeros (discarded)
    f16x8 z = {};
    *(f16x8*)(attn_l + t * 8) = z;
  }
  // zero every row's 2-f16 pad: P5 A-fragments read them as k=16,17 junk against
  // zero attn rows — junk must be finite (NaN x 0 = NaN), so pads must be 0/finite.
#pragma unroll
  for (int it = 0; it < 4; ++it) {
    int e = it * 256 + t, px = e >> 8, ci = e & 255;
    *(unsigned*)(cip + px * 4608 + ci * 18 + 16) = 0;
  }
  // stage feat patch: thread -> (px, r, ci) float4 (cols px*4..+3 = p r*4..+3 of pixel px)
  const float* fb = feat + (size_t)bb * (CDIM * 16384) + (h * 4) * 128 + w4 * 16;
#pragma unroll
  for (int it = 0; it < 16; ++it) {
    int e = it * 256 + t, px = e & 3, r = (e >> 2) & 3, ci = e >> 4;
    float4 v = *(const float4*)(fb + (size_t)ci * 16384 + r * 128 + px * 4);
    unsigned* d = (unsigned*)(cip + px * 4608 + ci * 18 + r * 4);  // 4B-aligned
    d[0] = pack2(v.x, v.y);
    d[1] = pack2(v.z, v.w);
  }
  __syncthreads();

  // ---- P3: logits[hd][p]; A from global qk (rows 8-15 alias 0-7, dupes discarded) ----
  const f16* qkg = qk + ((size_t)(bz * 1024 + pixb + w) * 8 + (l15 & 7)) * CDIM;
  const f16* cw = cip + w * 4608;
  f32x4 acc = {};
#pragma unroll
  for (int kb = 0; kb < 8; ++kb) {
    f16x8 a = *(const f16x8*)(qkg + kb * 32 + h4 * 8);  // A[hd][ci], k contiguous
    f16x8 bf;                                           // B[ci][p]: 8 x u16, conflict-free
#pragma unroll
    for (int j = 0; j < 8; ++j) bf[j] = cw[(kb * 32 + h4 * 8 + j) * 18 + l15];
    acc = MFMA(a, bf, acc);
  }
  // ---- softmax over p (= lane&15), hd = 4*h4 + r (h4<2 real, rest dupes) ----
  float at[4];
#pragma unroll
  for (int r = 0; r < 4; ++r) {
    float m = acc[r];
    m = fmaxf(m, __shfl_xor(m, 1, 64));
    m = fmaxf(m, __shfl_xor(m, 2, 64));
    m = fmaxf(m, __shfl_xor(m, 4, 64));
    m = fmaxf(m, __shfl_xor(m, 8, 64));
    float e = __expf(acc[r] - m);
    float s = e;
    s += __shfl_xor(s, 1, 64);
    s += __shfl_xor(s, 2, 64);
    s += __shfl_xor(s, 4, 64);
    s += __shfl_xor(s, 8, 64);
    at[r] = e / s;
  }
  if (h4 < 2) {  // store attn TRANSPOSED: [p][hd]
#pragma unroll
    for (int r = 0; r < 4; ++r) attn_l[w * 512 + l15 * 16 + h4 * 4 + r] = (f16)at[r];
  }
  // ---- P5'': D[m=ci_loc][n=hd] = A(feat)[ci][32p] @ B(attn)[32p][16hd] ----
  // same-wave LDS RAW on attn_l (in-order DS pipe; round-6-proven pattern)
  f16x8 b5;  // B[k=p][n=hd], loop-invariant
#pragma unroll
  for (int j = 0; j < 8; ++j) b5[j] = attn_l[w * 512 + (h4 * 8 + j) * 16 + l15];
  const f32x4 zero = {};
#pragma unroll
  for (int nt = 0; nt < 16; ++nt) {
    // A[m=ci][k=p]: 16B at 4B alignment (stride-18 rows); k>=16 junk x attn-zeros
    const unsigned* ap = (const unsigned*)(cw + (nt * 16 + l15) * 18 + h4 * 8);
    union { unsigned u[4]; f16x8 h; } A;
    A.u[0] = ap[0]; A.u[1] = ap[1]; A.u[2] = ap[2]; A.u[3] = ap[3];
    f32x4 d = MFMA(A.h, b5, zero);
    if (l15 < 8) {  // n = l15 = hd (0..7 real); m = 4*h4 + r -> ci contiguous
      union { f16 h[4]; unsigned long long u; } P;
      P.h[0] = (f16)d[0]; P.h[1] = (f16)d[1]; P.h[2] = (f16)d[2]; P.h[3] = (f16)d[3];
      *(unsigned long long*)(fa + ((size_t)(bz * 8 + l15) * 1024 + pixb + w) * CDIM +
                             nt * 16 + h4 * 4) = P.u;
    }
  }
}

// ---------------- K3: out[c][pix] = (wv @ fa + bv) * gw ----------------
// grid (16 pix-64, 8 hd, nb) x 256. M=64pix, N=32c, K=256ci.
__global__ __launch_bounds__(256) void k_out(const f16* __restrict__ fa,
                                             const f16* __restrict__ wvh,
                                             const float* __restrict__ bv,
                                             const float* __restrict__ gw,
                                             float* __restrict__ out, int b0) {
  __shared__ __align__(16) f16 wv_l[32 * 264];  // [c][256ci +8pad] 16896 B
  __shared__ __align__(16) f16 fa_l[64 * 40];   // [pix][32ci +8pad] 5120 B
  const int t = threadIdx.x;
  const int p16 = blockIdx.x, hd = blockIdx.y, bz = blockIdx.z;
  const int bb = b0 + bz;
  const int lane = t & 63, wid = t >> 6, l15 = lane & 15, h4 = lane >> 4;
#pragma unroll
  for (int it = 0; it < 4; ++it) {
    int e = it * 256 + t, c = e >> 5, ch = e & 31;
    *(f16x8*)(wv_l + c * 264 + ch * 8) =
        *(const f16x8*)(wvh + (size_t)(hd * 32 + c) * CDIM + ch * 8);
  }
  f32x4 acc[2] = {};
  for (int kb = 0; kb < 8; ++kb) {
    __syncthreads();
    {
      int pixl = t >> 2, q = t & 3;
      *(f16x8*)(fa_l + pixl * 40 + q * 8) =
          *(const f16x8*)(fa + ((size_t)(bz * 8 + hd) * 1024 + p16 * 64 + pixl) * CDIM +
                          kb * 32 + q * 8);
    }
    __syncthreads();
    f16x8 a = *(const f16x8*)(fa_l + (wid * 16 + l15) * 40 + h4 * 8);  // A[pix][ci]
#pragma unroll
    for (int nt = 0; nt < 2; ++nt) {
      f16x8 b = *(const f16x8*)(wv_l + (nt * 16 + l15) * 264 + kb * 32 + h4 * 8);  // B[ci][c]
      acc[nt] = MFMA(a, b, acc[nt]);
    }
  }
  int pix0 = p16 * 64 + wid * 16 + h4 * 4;
  float4 g = *(const float4*)(gw + bz * 1024 + pix0);
#pragma unroll
  for (int nt = 0; nt < 2; ++nt) {
    int c = hd * 32 + nt * 16 + l15;
    float bvc = bv[c];
    float4 o;
    o.x = (acc[nt][0] + bvc) * g.x;
    o.y = (acc[nt][1] + bvc) * g.y;
    o.z = (acc[nt][2] + bvc) * g.z;
    o.w = (acc[nt][3] + bvc) * g.w;
    *(float4*)(out + (size_t)(bb * CDIM + c) * 1024 + pix0) = o;
  }
}

// ---------------- launcher ----------------
extern "C" void kernel_launch(void* const* d_in, const int* in_sizes, int n_in,
                              void* d_out, int out_size, void* d_ws, size_t ws_size,
                              hipStream_t stream) {
  const float* x = (const float*)d_in[0];
  const float* feat = (const float*)d_in[1];
  const float* wq = (const float*)d_in[2];
  const float* bq = (const float*)d_in[3];
  const float* wk = (const float*)d_in[4];
  // d_in[5] = bk: constant over grid positions -> cancels in softmax, unused
  const float* wv = (const float*)d_in[6];
  const float* bv = (const float*)d_in[7];
  const float* wg = (const float*)d_in[8];
  const float* bg = (const float*)d_in[9];
  float* out = (float*)d_out;

  char* ws = (char*)d_ws;
  f16* W2h = (f16*)ws;                 // 1,048,576 B
  float* b2 = (float*)(ws + 1048576);  //     8,192 B
  f16* wvh = (f16*)(ws + 1056768);     //   131,072 B
  char* dyn = ws + 1187840;

  k_prep_w2<<<dim3(32, 8), 256, 0, stream>>>(wq, bq, wk, wv, W2h, b2, wvh);

  const size_t QK = 4194304, FA = 4194304, GW = 4096;  // per batch
  if (ws_size >= 1187840 + 8 * (QK + FA + GW)) {
    f16* qkp = (f16*)dyn;
    f16* fap = (f16*)(dyn + 8 * QK);
    float* gwp = (float*)(dyn + 8 * (QK + FA));
    k_qkw2<<<dim3(16, 8, 8), 256, 0, stream>>>(x, W2h, b2, wg, bg, qkp, gwp, 0);
    k_attn<<<dim3(32, 8, 8), 256, 0, stream>>>(feat, qkp, fap, 0);
    k_out<<<dim3(16, 8, 8), 256, 0, stream>>>(fap, wvh, bv, gwp, out, 0);
  } else {  // per-batch fallback (~9.6 MB workspace)
    f16* qkp = (f16*)dyn;
    f16* fap = (f16*)(dyn + QK);
    float* gwp = (float*)(dyn + QK + FA);
    for (int b = 0; b < 8; ++b) {
      k_qkw2<<<dim3(16, 8, 1), 256, 0, stream>>>(x, W2h, b2, wg, bg, qkp, gwp, b);
      k_attn<<<dim3(32, 8, 1), 256, 0, stream>>>(feat, qkp, fap, b);
      k_out<<<dim3(16, 8, 1), 256, 0, stream>>>(fap, wvh, bv, gwp, out, b);
    }
  }
}